// Round 1
// baseline (3045.367 us; speedup 1.0000x reference)
//
#include <hip/hip_runtime.h>

#define N_NODES 200000
#define N_EDGES 3200000
#define N_GRAPHS 64
#define SDIM 16
#define ADIM 8
#define H1 40
#define G1 24
#define H2 24
#define G2 24
#define EPS_BN 1e-5f

static __device__ __forceinline__ float rdeg(float d) {
    return 1.0f / sqrtf(fmaxf(d, 1.0f));
}

// ---- degrees -------------------------------------------------------------
__global__ __launch_bounds__(256) void k_deg(const int* __restrict__ src,
                                             const int* __restrict__ dst,
                                             float* __restrict__ outdeg,
                                             float* __restrict__ indeg) {
    int e = blockIdx.x * 256 + threadIdx.x;
    if (e < N_EDGES) {
        atomicAdd(&outdeg[src[e]], 1.0f);
        atomicAdd(&indeg[dst[e]], 1.0f);
    }
}

// ---- fc1 + BN statistics (sum, sumsq per feature) ------------------------
__global__ __launch_bounds__(256) void k_bnstat(const float* __restrict__ nd,
                                                const float* __restrict__ nr,
                                                const float* __restrict__ fc1w,
                                                const float* __restrict__ fc1b,
                                                float* __restrict__ stats) {
    __shared__ float sw[H1 * SDIM];
    __shared__ float sb[H1];
    __shared__ float wsum[4][H1];
    __shared__ float wsq[4][H1];
    int t = threadIdx.x;
    for (int i = t; i < H1 * SDIM; i += 256) sw[i] = fc1w[i];
    if (t < H1) sb[t] = fc1b[t];
    __syncthreads();

    int i = blockIdx.x * 256 + t;
    bool valid = i < N_NODES;
    float x[SDIM];
    if (valid) {
        const float4* p0 = (const float4*)(nd + (size_t)i * 8);
        const float4* p1 = (const float4*)(nr + (size_t)i * 8);
        float4 a0 = p0[0], a1 = p0[1], b0 = p1[0], b1 = p1[1];
        x[0]=a0.x; x[1]=a0.y; x[2]=a0.z; x[3]=a0.w;
        x[4]=a1.x; x[5]=a1.y; x[6]=a1.z; x[7]=a1.w;
        x[8]=b0.x; x[9]=b0.y; x[10]=b0.z; x[11]=b0.w;
        x[12]=b1.x; x[13]=b1.y; x[14]=b1.z; x[15]=b1.w;
    } else {
        #pragma unroll
        for (int k = 0; k < SDIM; ++k) x[k] = 0.f;
    }
    int lane = t & 63, w = t >> 6;
    for (int k = 0; k < H1; ++k) {
        float acc = sb[k];
        #pragma unroll
        for (int m = 0; m < SDIM; ++m) acc += x[m] * sw[k * SDIM + m];
        float h = valid ? fmaxf(acc, 0.f) : 0.f;
        float s = h, q = h * h;
        #pragma unroll
        for (int off = 32; off > 0; off >>= 1) {
            s += __shfl_xor(s, off);
            q += __shfl_xor(q, off);
        }
        if (lane == 0) { wsum[w][k] = s; wsq[w][k] = q; }
    }
    __syncthreads();
    if (t < H1) {
        float s = wsum[0][t] + wsum[1][t] + wsum[2][t] + wsum[3][t];
        float q = wsq[0][t] + wsq[1][t] + wsq[2][t] + wsq[3][t];
        atomicAdd(&stats[t], s);
        atomicAdd(&stats[H1 + t], q);
    }
}

// ---- fold BN affine into conv1 weight ------------------------------------
__global__ __launch_bounds__(256) void k_fold(const float* __restrict__ stats,
                                              const float* __restrict__ bng,
                                              const float* __restrict__ bnb,
                                              const float* __restrict__ c1w,
                                              float* __restrict__ W1p,
                                              float* __restrict__ cb1) {
    __shared__ float a[H1], c[H1];
    int t = threadIdx.x;
    if (t < H1) {
        float mu  = stats[t] * (1.0f / N_NODES);
        float var = stats[H1 + t] * (1.0f / N_NODES) - mu * mu;
        float av  = bng[t] / sqrtf(var + EPS_BN);
        a[t] = av;
        c[t] = bnb[t] - mu * av;
    }
    __syncthreads();
    for (int i = t; i < H1 * G1; i += 256) {
        int k = i / G1;
        W1p[i] = a[k] * c1w[i];
    }
    if (t < G1) {
        float acc = 0.f;
        for (int k = 0; k < H1; ++k) acc += c[k] * c1w[k * G1 + t];
        cb1[t] = acc;
    }
}

// ---- recompute fc1, apply folded BN+conv1 weight, scale by cs ------------
__global__ __launch_bounds__(256) void k_pre1(const float* __restrict__ nd,
                                              const float* __restrict__ nr,
                                              const float* __restrict__ fc1w,
                                              const float* __restrict__ fc1b,
                                              const float* __restrict__ W1p,
                                              const float* __restrict__ cb1,
                                              const float* __restrict__ outdeg,
                                              float* __restrict__ pre) {
    __shared__ float sw[H1 * SDIM];
    __shared__ float sb[H1];
    __shared__ float sW[H1 * G1];
    __shared__ float scb[G1];
    int t = threadIdx.x;
    for (int i = t; i < H1 * SDIM; i += 256) sw[i] = fc1w[i];
    for (int i = t; i < H1 * G1; i += 256) sW[i] = W1p[i];
    if (t < H1) sb[t] = fc1b[t];
    if (t < G1) scb[t] = cb1[t];
    __syncthreads();

    int i = blockIdx.x * 256 + t;
    if (i >= N_NODES) return;

    float x[SDIM];
    {
        const float4* p0 = (const float4*)(nd + (size_t)i * 8);
        const float4* p1 = (const float4*)(nr + (size_t)i * 8);
        float4 a0 = p0[0], a1 = p0[1], b0 = p1[0], b1 = p1[1];
        x[0]=a0.x; x[1]=a0.y; x[2]=a0.z; x[3]=a0.w;
        x[4]=a1.x; x[5]=a1.y; x[6]=a1.z; x[7]=a1.w;
        x[8]=b0.x; x[9]=b0.y; x[10]=b0.z; x[11]=b0.w;
        x[12]=b1.x; x[13]=b1.y; x[14]=b1.z; x[15]=b1.w;
    }
    float o[G1];
    #pragma unroll
    for (int j = 0; j < G1; ++j) o[j] = scb[j];
    for (int k = 0; k < H1; ++k) {
        float acc = sb[k];
        #pragma unroll
        for (int m = 0; m < SDIM; ++m) acc += x[m] * sw[k * SDIM + m];
        float h = fmaxf(acc, 0.f);
        #pragma unroll
        for (int j = 0; j < G1; ++j) o[j] += h * sW[k * G1 + j];
    }
    float cs = rdeg(outdeg[i]);
    float4* dp = (float4*)(pre + (size_t)i * G1);
    #pragma unroll
    for (int q = 0; q < 6; ++q)
        dp[q] = make_float4(o[4*q]*cs, o[4*q+1]*cs, o[4*q+2]*cs, o[4*q+3]*cs);
}

// ---- edge scatter: agg[dst] += pre[src]  (thread = (edge, float4-quad)) --
__global__ __launch_bounds__(256) void k_edge(const int* __restrict__ src,
                                              const int* __restrict__ dst,
                                              const float* __restrict__ pre,
                                              float* __restrict__ agg) {
    int t = blockIdx.x * 256 + threadIdx.x;
    if (t >= N_EDGES * 6) return;
    int e = t / 6;
    int q = t - e * 6;
    int s = src[e], d = dst[e];
    const float4 v = *(const float4*)(pre + (size_t)s * G1 + q * 4);
    float* ap = agg + (size_t)d * G1 + q * 4;
    atomicAdd(ap + 0, v.x);
    atomicAdd(ap + 1, v.y);
    atomicAdd(ap + 2, v.z);
    atomicAdd(ap + 3, v.w);
}

// ---- finalize conv1, fc2+relu, pre-multiply conv2 weight and cs ----------
__global__ __launch_bounds__(256) void k_fc2(const float* __restrict__ agg1,
                                             const float* __restrict__ action,
                                             const float* __restrict__ c1b,
                                             const float* __restrict__ fc2w,
                                             const float* __restrict__ fc2b,
                                             const float* __restrict__ c2w,
                                             const float* __restrict__ outdeg,
                                             const float* __restrict__ indeg,
                                             float* __restrict__ pre2) {
    __shared__ float s2w[H2 * (G1 + ADIM)];
    __shared__ float s2b[H2];
    __shared__ float scw[H2 * G2];
    __shared__ float s1b[G1];
    int t = threadIdx.x;
    for (int i = t; i < H2 * (G1 + ADIM); i += 256) s2w[i] = fc2w[i];
    for (int i = t; i < H2 * G2; i += 256) scw[i] = c2w[i];
    if (t < H2) s2b[t] = fc2b[t];
    if (t < G1) s1b[t] = c1b[t];
    __syncthreads();

    int i = blockIdx.x * 256 + t;
    if (i >= N_NODES) return;

    float cd = rdeg(indeg[i]);
    float x[G1 + ADIM];
    {
        const float4* ap = (const float4*)(agg1 + (size_t)i * G1);
        #pragma unroll
        for (int q = 0; q < 6; ++q) {
            float4 v = ap[q];
            x[4*q+0] = v.x * cd + s1b[4*q+0];
            x[4*q+1] = v.y * cd + s1b[4*q+1];
            x[4*q+2] = v.z * cd + s1b[4*q+2];
            x[4*q+3] = v.w * cd + s1b[4*q+3];
        }
        const float4* cp = (const float4*)(action + (size_t)i * ADIM);
        float4 a0 = cp[0], a1 = cp[1];
        x[24]=a0.x; x[25]=a0.y; x[26]=a0.z; x[27]=a0.w;
        x[28]=a1.x; x[29]=a1.y; x[30]=a1.z; x[31]=a1.w;
    }
    float h2[H2];
    for (int k = 0; k < H2; ++k) {
        float acc = s2b[k];
        #pragma unroll
        for (int j = 0; j < G1 + ADIM; ++j) acc += x[j] * s2w[k * (G1 + ADIM) + j];
        h2[k] = fmaxf(acc, 0.f);
    }
    float o[G2];
    #pragma unroll
    for (int j = 0; j < G2; ++j) o[j] = 0.f;
    for (int k = 0; k < H2; ++k) {
        float hv = h2[k];
        #pragma unroll
        for (int j = 0; j < G2; ++j) o[j] += hv * scw[k * G2 + j];
    }
    float cs = rdeg(outdeg[i]);
    float4* dp = (float4*)(pre2 + (size_t)i * G2);
    #pragma unroll
    for (int q = 0; q < 6; ++q)
        dp[q] = make_float4(o[4*q]*cs, o[4*q+1]*cs, o[4*q+2]*cs, o[4*q+3]*cs);
}

// ---- per-graph pooling of cd*(agg2 @ fc3w) -------------------------------
__global__ __launch_bounds__(256) void k_pool(const float* __restrict__ agg2,
                                              const float* __restrict__ indeg,
                                              const int* __restrict__ gid,
                                              const float* __restrict__ fc3w,
                                              float* __restrict__ gsum,
                                              float* __restrict__ gcnt) {
    __shared__ float s3[G2];
    __shared__ float ss[N_GRAPHS];
    __shared__ float sc[N_GRAPHS];
    int t = threadIdx.x;
    if (t < G2) s3[t] = fc3w[t];
    if (t < N_GRAPHS) { ss[t] = 0.f; sc[t] = 0.f; }
    __syncthreads();
    int i = blockIdx.x * 256 + t;
    if (i < N_NODES) {
        float cd = rdeg(indeg[i]);
        const float4* ap = (const float4*)(agg2 + (size_t)i * G2);
        float s = 0.f;
        #pragma unroll
        for (int q = 0; q < 6; ++q) {
            float4 v = ap[q];
            s += v.x * s3[4*q] + v.y * s3[4*q+1] + v.z * s3[4*q+2] + v.w * s3[4*q+3];
        }
        int g = gid[i];
        atomicAdd(&ss[g], s * cd);
        atomicAdd(&sc[g], 1.0f);
    }
    __syncthreads();
    if (t < N_GRAPHS && sc[t] != 0.f) {
        atomicAdd(&gsum[t], ss[t]);
        atomicAdd(&gcnt[t], sc[t]);
    }
}

// ---- final: mean + folded bias terms -------------------------------------
__global__ __launch_bounds__(64) void k_final(const float* __restrict__ gsum,
                                              const float* __restrict__ gcnt,
                                              const float* __restrict__ c2b,
                                              const float* __restrict__ fc3w,
                                              const float* __restrict__ fc3b,
                                              float* __restrict__ out) {
    int t = threadIdx.x;
    __shared__ float base;
    if (t == 0) {
        float a = 0.f;
        for (int j = 0; j < G2; ++j) a += c2b[j] * fc3w[j];
        base = a + fc3b[0];
    }
    __syncthreads();
    if (t < N_GRAPHS) out[t] = gsum[t] / fmaxf(gcnt[t], 1.f) + base;
}

extern "C" void kernel_launch(void* const* d_in, const int* in_sizes, int n_in,
                              void* d_out, int out_size, void* d_ws, size_t ws_size,
                              hipStream_t stream) {
    const float* nd     = (const float*)d_in[0];
    const float* nr     = (const float*)d_in[1];
    const float* action = (const float*)d_in[2];
    const int*   src    = (const int*)d_in[3];
    const int*   dst    = (const int*)d_in[4];
    const int*   gid    = (const int*)d_in[5];
    const float* fc1w   = (const float*)d_in[6];
    const float* fc1b   = (const float*)d_in[7];
    const float* bng    = (const float*)d_in[8];
    const float* bnb    = (const float*)d_in[9];
    const float* c1w    = (const float*)d_in[10];
    const float* c1b    = (const float*)d_in[11];
    const float* fc2w   = (const float*)d_in[12];
    const float* fc2b   = (const float*)d_in[13];
    const float* c2w    = (const float*)d_in[14];
    const float* c2b    = (const float*)d_in[15];
    const float* fc3w   = (const float*)d_in[16];
    const float* fc3b   = (const float*)d_in[17];
    float* out = (float*)d_out;

    float* ws = (float*)d_ws;
    const size_t N = N_NODES;
    float* outdeg = ws;
    float* indeg  = ws + N;
    float* pre    = ws + 2 * N;        // [N,24], reused as pre1 then pre2
    float* agg    = ws + 26 * N;       // [N,24], reused as agg1 then agg2
    float* stats  = ws + 50 * N;       // 80 floats
    float* W1p    = stats + 2 * H1;    // 960
    float* cb1    = W1p + H1 * G1;     // 24
    float* gsum   = cb1 + G1;          // 64
    float* gcnt   = gsum + N_GRAPHS;   // 64

    hipMemsetAsync(outdeg, 0, 2 * N * sizeof(float), stream);
    hipMemsetAsync(agg, 0, 24 * N * sizeof(float), stream);
    hipMemsetAsync(stats, 0, (2 * H1 + H1 * G1 + G1 + 2 * N_GRAPHS) * sizeof(float), stream);

    int nb_edges = (N_EDGES + 255) / 256;
    int nb_nodes = (N_NODES + 255) / 256;
    int nb_e6    = (N_EDGES * 6 + 255) / 256;

    k_deg<<<nb_edges, 256, 0, stream>>>(src, dst, outdeg, indeg);
    k_bnstat<<<nb_nodes, 256, 0, stream>>>(nd, nr, fc1w, fc1b, stats);
    k_fold<<<1, 256, 0, stream>>>(stats, bng, bnb, c1w, W1p, cb1);
    k_pre1<<<nb_nodes, 256, 0, stream>>>(nd, nr, fc1w, fc1b, W1p, cb1, outdeg, pre);
    k_edge<<<nb_e6, 256, 0, stream>>>(src, dst, pre, agg);
    k_fc2<<<nb_nodes, 256, 0, stream>>>(agg, action, c1b, fc2w, fc2b, c2w, outdeg, indeg, pre);
    hipMemsetAsync(agg, 0, 24 * N * sizeof(float), stream);
    k_edge<<<nb_e6, 256, 0, stream>>>(src, dst, pre, agg);
    k_pool<<<nb_nodes, 256, 0, stream>>>(agg, indeg, gid, fc3w, gsum, gcnt);
    k_final<<<1, 64, 0, stream>>>(gsum, gcnt, c2b, fc3w, fc3b, out);
}

// Round 2
// 638.487 us; speedup vs baseline: 4.7697x; 4.7697x over previous
//
#include <hip/hip_runtime.h>

#define N_NODES 200000
#define N_EDGES 3200000
#define N_GRAPHS 64
#define SDIM 16
#define ADIM 8
#define H1 40
#define G1 24
#define H2 24
#define G2 24
#define EPS_BN 1e-5f
#define NB_NODES ((N_NODES + 255) / 256)   // 782
#define PRE_STRIDE 32                       // pad 24-float rows to 128B

static __device__ __forceinline__ float rdeg(float d) {
    return 1.0f / sqrtf(fmaxf(d, 1.0f));
}

// ---- integer degrees -----------------------------------------------------
__global__ __launch_bounds__(256) void k_deg(const int* __restrict__ src,
                                             const int* __restrict__ dst,
                                             int* __restrict__ outdeg,
                                             int* __restrict__ indeg) {
    int e = blockIdx.x * 256 + threadIdx.x;
    if (e < N_EDGES) {
        atomicAdd(&outdeg[src[e]], 1);
        atomicAdd(&indeg[dst[e]], 1);
    }
}

// ---- block-level exclusive scan of indeg ---------------------------------
__global__ __launch_bounds__(256) void k_scan_block(const int* __restrict__ indeg,
                                                    int* __restrict__ rowstart,
                                                    int* __restrict__ bsum) {
    __shared__ int s[256];
    int t = threadIdx.x;
    int i = blockIdx.x * 256 + t;
    int v = (i < N_NODES) ? indeg[i] : 0;
    s[t] = v;
    __syncthreads();
    for (int off = 1; off < 256; off <<= 1) {
        int add = (t >= off) ? s[t - off] : 0;
        __syncthreads();
        s[t] += add;
        __syncthreads();
    }
    if (i < N_NODES) rowstart[i] = s[t] - v;
    if (t == 255) bsum[blockIdx.x] = s[255];
}

__global__ __launch_bounds__(1024) void k_scan_top(int* __restrict__ bsum) {
    __shared__ int s[1024];
    int t = threadIdx.x;
    int v = (t < NB_NODES) ? bsum[t] : 0;
    s[t] = v;
    __syncthreads();
    for (int off = 1; off < 1024; off <<= 1) {
        int add = (t >= off) ? s[t - off] : 0;
        __syncthreads();
        s[t] += add;
        __syncthreads();
    }
    if (t < NB_NODES) bsum[t] = s[t] - v;   // exclusive block offsets
}

__global__ __launch_bounds__(256) void k_scan_add(int* __restrict__ rowstart,
                                                  const int* __restrict__ bsum) {
    int i = blockIdx.x * 256 + threadIdx.x;
    if (i < N_NODES) rowstart[i] += bsum[blockIdx.x];
}

// ---- CSR fill (counting sort of edges by dst) ----------------------------
__global__ __launch_bounds__(256) void k_fill(const int* __restrict__ src,
                                              const int* __restrict__ dst,
                                              const int* __restrict__ rowstart,
                                              int* __restrict__ cursor,
                                              int* __restrict__ csr) {
    int e = blockIdx.x * 256 + threadIdx.x;
    if (e < N_EDGES) {
        int d = dst[e];
        int slot = atomicAdd(&cursor[d], 1);
        csr[rowstart[d] + slot] = src[e];
    }
}

// ---- fc1 + BN statistics (sum, sumsq per feature) ------------------------
__global__ __launch_bounds__(256) void k_bnstat(const float* __restrict__ nd,
                                                const float* __restrict__ nr,
                                                const float* __restrict__ fc1w,
                                                const float* __restrict__ fc1b,
                                                float* __restrict__ stats) {
    __shared__ float sw[H1 * SDIM];
    __shared__ float sb[H1];
    __shared__ float wsum[4][H1];
    __shared__ float wsq[4][H1];
    int t = threadIdx.x;
    for (int i = t; i < H1 * SDIM; i += 256) sw[i] = fc1w[i];
    if (t < H1) sb[t] = fc1b[t];
    __syncthreads();

    int i = blockIdx.x * 256 + t;
    bool valid = i < N_NODES;
    float x[SDIM];
    if (valid) {
        const float4* p0 = (const float4*)(nd + (size_t)i * 8);
        const float4* p1 = (const float4*)(nr + (size_t)i * 8);
        float4 a0 = p0[0], a1 = p0[1], b0 = p1[0], b1 = p1[1];
        x[0]=a0.x; x[1]=a0.y; x[2]=a0.z; x[3]=a0.w;
        x[4]=a1.x; x[5]=a1.y; x[6]=a1.z; x[7]=a1.w;
        x[8]=b0.x; x[9]=b0.y; x[10]=b0.z; x[11]=b0.w;
        x[12]=b1.x; x[13]=b1.y; x[14]=b1.z; x[15]=b1.w;
    } else {
        #pragma unroll
        for (int k = 0; k < SDIM; ++k) x[k] = 0.f;
    }
    int lane = t & 63, w = t >> 6;
    for (int k = 0; k < H1; ++k) {
        float acc = sb[k];
        #pragma unroll
        for (int m = 0; m < SDIM; ++m) acc += x[m] * sw[k * SDIM + m];
        float h = valid ? fmaxf(acc, 0.f) : 0.f;
        float s = h, q = h * h;
        #pragma unroll
        for (int off = 32; off > 0; off >>= 1) {
            s += __shfl_xor(s, off);
            q += __shfl_xor(q, off);
        }
        if (lane == 0) { wsum[w][k] = s; wsq[w][k] = q; }
    }
    __syncthreads();
    if (t < H1) {
        float s = wsum[0][t] + wsum[1][t] + wsum[2][t] + wsum[3][t];
        float q = wsq[0][t] + wsq[1][t] + wsq[2][t] + wsq[3][t];
        atomicAdd(&stats[t], s);
        atomicAdd(&stats[H1 + t], q);
    }
}

// ---- fold BN affine into conv1 weight ------------------------------------
__global__ __launch_bounds__(256) void k_fold(const float* __restrict__ stats,
                                              const float* __restrict__ bng,
                                              const float* __restrict__ bnb,
                                              const float* __restrict__ c1w,
                                              float* __restrict__ W1p,
                                              float* __restrict__ cb1) {
    __shared__ float a[H1], c[H1];
    int t = threadIdx.x;
    if (t < H1) {
        float mu  = stats[t] * (1.0f / N_NODES);
        float var = stats[H1 + t] * (1.0f / N_NODES) - mu * mu;
        float av  = bng[t] / sqrtf(var + EPS_BN);
        a[t] = av;
        c[t] = bnb[t] - mu * av;
    }
    __syncthreads();
    for (int i = t; i < H1 * G1; i += 256) {
        int k = i / G1;
        W1p[i] = a[k] * c1w[i];
    }
    if (t < G1) {
        float acc = 0.f;
        for (int k = 0; k < H1; ++k) acc += c[k] * c1w[k * G1 + t];
        cb1[t] = acc;
    }
}

// ---- recompute fc1, folded BN+conv1 weight, scale by cs; padded rows -----
__global__ __launch_bounds__(256) void k_pre1(const float* __restrict__ nd,
                                              const float* __restrict__ nr,
                                              const float* __restrict__ fc1w,
                                              const float* __restrict__ fc1b,
                                              const float* __restrict__ W1p,
                                              const float* __restrict__ cb1,
                                              const int* __restrict__ outdeg,
                                              float* __restrict__ pre) {
    __shared__ float sw[H1 * SDIM];
    __shared__ float sb[H1];
    __shared__ float sW[H1 * G1];
    __shared__ float scb[G1];
    int t = threadIdx.x;
    for (int i = t; i < H1 * SDIM; i += 256) sw[i] = fc1w[i];
    for (int i = t; i < H1 * G1; i += 256) sW[i] = W1p[i];
    if (t < H1) sb[t] = fc1b[t];
    if (t < G1) scb[t] = cb1[t];
    __syncthreads();

    int i = blockIdx.x * 256 + t;
    if (i >= N_NODES) return;

    float x[SDIM];
    {
        const float4* p0 = (const float4*)(nd + (size_t)i * 8);
        const float4* p1 = (const float4*)(nr + (size_t)i * 8);
        float4 a0 = p0[0], a1 = p0[1], b0 = p1[0], b1 = p1[1];
        x[0]=a0.x; x[1]=a0.y; x[2]=a0.z; x[3]=a0.w;
        x[4]=a1.x; x[5]=a1.y; x[6]=a1.z; x[7]=a1.w;
        x[8]=b0.x; x[9]=b0.y; x[10]=b0.z; x[11]=b0.w;
        x[12]=b1.x; x[13]=b1.y; x[14]=b1.z; x[15]=b1.w;
    }
    float o[G1];
    #pragma unroll
    for (int j = 0; j < G1; ++j) o[j] = scb[j];
    for (int k = 0; k < H1; ++k) {
        float acc = sb[k];
        #pragma unroll
        for (int m = 0; m < SDIM; ++m) acc += x[m] * sw[k * SDIM + m];
        float h = fmaxf(acc, 0.f);
        #pragma unroll
        for (int j = 0; j < G1; ++j) o[j] += h * sW[k * G1 + j];
    }
    float cs = rdeg((float)outdeg[i]);
    float4* dp = (float4*)(pre + (size_t)i * PRE_STRIDE);
    #pragma unroll
    for (int q = 0; q < 6; ++q)
        dp[q] = make_float4(o[4*q]*cs, o[4*q+1]*cs, o[4*q+2]*cs, o[4*q+3]*cs);
}

// ---- gather conv1, fc2+relu, conv2-weight, fold fc3 to scalar t ----------
__global__ __launch_bounds__(256) void k_conv1fc2(const int* __restrict__ rowstart,
                                                  const int* __restrict__ indeg,
                                                  const int* __restrict__ outdeg,
                                                  const int* __restrict__ csr,
                                                  const float* __restrict__ pre,
                                                  const float* __restrict__ action,
                                                  const float* __restrict__ c1b,
                                                  const float* __restrict__ fc2w,
                                                  const float* __restrict__ fc2b,
                                                  const float* __restrict__ c2w,
                                                  const float* __restrict__ fc3w,
                                                  float* __restrict__ tbuf) {
    __shared__ float s2w[H2 * (G1 + ADIM)];
    __shared__ float s2b[H2];
    __shared__ float scw[H2 * G2];
    __shared__ float s1b[G1];
    __shared__ float s3[G2];
    int t = threadIdx.x;
    for (int i = t; i < H2 * (G1 + ADIM); i += 256) s2w[i] = fc2w[i];
    for (int i = t; i < H2 * G2; i += 256) scw[i] = c2w[i];
    if (t < H2) s2b[t] = fc2b[t];
    if (t < G1) s1b[t] = c1b[t];
    if (t < G2) s3[t] = fc3w[t];
    __syncthreads();

    int i = blockIdx.x * 256 + t;
    if (i >= N_NODES) return;

    float4 a[6];
    #pragma unroll
    for (int q = 0; q < 6; ++q) a[q] = make_float4(0.f, 0.f, 0.f, 0.f);
    int rs = rowstart[i];
    int d  = indeg[i];
    for (int j = rs; j < rs + d; ++j) {
        int s = csr[j];
        const float4* p = (const float4*)(pre + (size_t)s * PRE_STRIDE);
        #pragma unroll
        for (int q = 0; q < 6; ++q) {
            float4 v = p[q];
            a[q].x += v.x; a[q].y += v.y; a[q].z += v.z; a[q].w += v.w;
        }
    }
    float cd = rdeg((float)d);
    float x[G1 + ADIM];
    #pragma unroll
    for (int q = 0; q < 6; ++q) {
        x[4*q+0] = a[q].x * cd + s1b[4*q+0];
        x[4*q+1] = a[q].y * cd + s1b[4*q+1];
        x[4*q+2] = a[q].z * cd + s1b[4*q+2];
        x[4*q+3] = a[q].w * cd + s1b[4*q+3];
    }
    {
        const float4* cp = (const float4*)(action + (size_t)i * ADIM);
        float4 a0 = cp[0], a1 = cp[1];
        x[24]=a0.x; x[25]=a0.y; x[26]=a0.z; x[27]=a0.w;
        x[28]=a1.x; x[29]=a1.y; x[30]=a1.z; x[31]=a1.w;
    }
    float o[G2];
    #pragma unroll
    for (int j = 0; j < G2; ++j) o[j] = 0.f;
    for (int k = 0; k < H2; ++k) {
        float acc = s2b[k];
        #pragma unroll
        for (int j = 0; j < G1 + ADIM; ++j) acc += x[j] * s2w[k * (G1 + ADIM) + j];
        float hv = fmaxf(acc, 0.f);
        #pragma unroll
        for (int j = 0; j < G2; ++j) o[j] += hv * scw[k * G2 + j];
    }
    // t[i] = cs_i * dot(o, fc3w): conv2's contribution of node i, fc3-folded
    float cs = rdeg((float)outdeg[i]);
    float tt = 0.f;
    #pragma unroll
    for (int j = 0; j < G2; ++j) tt += o[j] * s3[j];
    tbuf[i] = tt * cs;
}

// ---- conv2 scalar gather + per-graph pooling -----------------------------
__global__ __launch_bounds__(256) void k_pool(const int* __restrict__ rowstart,
                                              const int* __restrict__ indeg,
                                              const int* __restrict__ csr,
                                              const float* __restrict__ tbuf,
                                              const int* __restrict__ gid,
                                              float* __restrict__ gsum,
                                              float* __restrict__ gcnt) {
    __shared__ float ss[N_GRAPHS];
    __shared__ float sc[N_GRAPHS];
    int t = threadIdx.x;
    if (t < N_GRAPHS) { ss[t] = 0.f; sc[t] = 0.f; }
    __syncthreads();
    int i = blockIdx.x * 256 + t;
    if (i < N_NODES) {
        int rs = rowstart[i];
        int d  = indeg[i];
        float s = 0.f;
        for (int j = rs; j < rs + d; ++j) s += tbuf[csr[j]];
        float cd = rdeg((float)d);
        atomicAdd(&ss[gid[i]], s * cd);
        atomicAdd(&sc[gid[i]], 1.0f);
    }
    __syncthreads();
    if (t < N_GRAPHS && sc[t] != 0.f) {
        atomicAdd(&gsum[t], ss[t]);
        atomicAdd(&gcnt[t], sc[t]);
    }
}

// ---- final: mean + folded bias terms -------------------------------------
__global__ __launch_bounds__(64) void k_final(const float* __restrict__ gsum,
                                              const float* __restrict__ gcnt,
                                              const float* __restrict__ c2b,
                                              const float* __restrict__ fc3w,
                                              const float* __restrict__ fc3b,
                                              float* __restrict__ out) {
    int t = threadIdx.x;
    __shared__ float base;
    if (t == 0) {
        float a = 0.f;
        for (int j = 0; j < G2; ++j) a += c2b[j] * fc3w[j];
        base = a + fc3b[0];
    }
    __syncthreads();
    if (t < N_GRAPHS) out[t] = gsum[t] / fmaxf(gcnt[t], 1.f) + base;
}

extern "C" void kernel_launch(void* const* d_in, const int* in_sizes, int n_in,
                              void* d_out, int out_size, void* d_ws, size_t ws_size,
                              hipStream_t stream) {
    const float* nd     = (const float*)d_in[0];
    const float* nr     = (const float*)d_in[1];
    const float* action = (const float*)d_in[2];
    const int*   src    = (const int*)d_in[3];
    const int*   dst    = (const int*)d_in[4];
    const int*   gid    = (const int*)d_in[5];
    const float* fc1w   = (const float*)d_in[6];
    const float* fc1b   = (const float*)d_in[7];
    const float* bng    = (const float*)d_in[8];
    const float* bnb    = (const float*)d_in[9];
    const float* c1w    = (const float*)d_in[10];
    const float* c1b    = (const float*)d_in[11];
    const float* fc2w   = (const float*)d_in[12];
    const float* fc2b   = (const float*)d_in[13];
    const float* c2w    = (const float*)d_in[14];
    const float* c2b    = (const float*)d_in[15];
    const float* fc3w   = (const float*)d_in[16];
    const float* fc3b   = (const float*)d_in[17];
    float* out = (float*)d_out;

    const size_t N = N_NODES;
    int* indeg    = (int*)d_ws;
    int* outdeg   = indeg + N;
    int* cursor   = outdeg + N;
    int* rowstart = cursor + N;
    int* bsum     = rowstart + N;          // 1024 slots
    int* csr      = bsum + 1024;           // E
    float* pre    = (float*)(csr + N_EDGES);   // [N, PRE_STRIDE], 128B rows
    float* tbuf   = pre + (size_t)N * PRE_STRIDE;
    float* stats  = tbuf + N;              // 80
    float* W1p    = stats + 2 * H1;        // 960
    float* cb1    = W1p + H1 * G1;         // 24
    float* gsum   = cb1 + G1;              // 64
    float* gcnt   = gsum + N_GRAPHS;       // 64

    hipMemsetAsync(indeg, 0, 3 * N * sizeof(int), stream);          // indeg,outdeg,cursor
    hipMemsetAsync(stats, 0, (2*H1 + H1*G1 + G1 + 2*N_GRAPHS) * sizeof(float), stream);

    int nb_edges = (N_EDGES + 255) / 256;
    int nb_nodes = NB_NODES;

    k_deg<<<nb_edges, 256, 0, stream>>>(src, dst, outdeg, indeg);
    k_bnstat<<<nb_nodes, 256, 0, stream>>>(nd, nr, fc1w, fc1b, stats);
    k_scan_block<<<nb_nodes, 256, 0, stream>>>(indeg, rowstart, bsum);
    k_scan_top<<<1, 1024, 0, stream>>>(bsum);
    k_scan_add<<<nb_nodes, 256, 0, stream>>>(rowstart, bsum);
    k_fill<<<nb_edges, 256, 0, stream>>>(src, dst, rowstart, cursor, csr);
    k_fold<<<1, 256, 0, stream>>>(stats, bng, bnb, c1w, W1p, cb1);
    k_pre1<<<nb_nodes, 256, 0, stream>>>(nd, nr, fc1w, fc1b, W1p, cb1, outdeg, pre);
    k_conv1fc2<<<nb_nodes, 256, 0, stream>>>(rowstart, indeg, outdeg, csr, pre,
                                             action, c1b, fc2w, fc2b, c2w, fc3w, tbuf);
    k_pool<<<nb_nodes, 256, 0, stream>>>(rowstart, indeg, csr, tbuf, gid, gsum, gcnt);
    k_final<<<1, 64, 0, stream>>>(gsum, gcnt, c2b, fc3w, fc3b, out);
}

// Round 3
// 564.566 us; speedup vs baseline: 5.3942x; 1.1309x over previous
//
#include <hip/hip_runtime.h>

#define N_NODES 200000
#define N_EDGES 3200000
#define N_GRAPHS 64
#define SDIM 16
#define ADIM 8
#define H1 40
#define G1 24
#define H2 24
#define G2 24
#define EPS_BN 1e-5f
#define NB_NODES ((N_NODES + 255) / 256)   // 782
#define PRE_U 16   // uints per pre row (32 bf16 = 64B, 24 used)

static __device__ __forceinline__ float rdeg(float d) {
    return 1.0f / sqrtf(fmaxf(d, 1.0f));
}

static __device__ __forceinline__ unsigned f2bf(float f) {
    union { float f; unsigned u; } v; v.f = f;
    return (v.u + 0x7fffu + ((v.u >> 16) & 1u)) >> 16;   // RNE to bf16
}
#define BF_LO(u) __uint_as_float((u) << 16)
#define BF_HI(u) __uint_as_float((u) & 0xffff0000u)

// ---- fused: outdeg count + dst-bucket CSR fill (counting sort) -----------
__global__ __launch_bounds__(256) void k_scatter(const int4* __restrict__ src4,
                                                 const int4* __restrict__ dst4,
                                                 int* __restrict__ cursor,
                                                 int* __restrict__ outdeg,
                                                 int* __restrict__ bucket,
                                                 int cmax) {
    int t = blockIdx.x * 256 + threadIdx.x;     // t < N_EDGES/4
    int4 s = src4[t];
    int4 d = dst4[t];
    int s0 = atomicAdd(&cursor[d.x], 1);
    int s1 = atomicAdd(&cursor[d.y], 1);
    int s2 = atomicAdd(&cursor[d.z], 1);
    int s3 = atomicAdd(&cursor[d.w], 1);
    if (s0 < cmax) bucket[d.x * cmax + s0] = s.x;
    if (s1 < cmax) bucket[d.y * cmax + s1] = s.y;
    if (s2 < cmax) bucket[d.z * cmax + s2] = s.z;
    if (s3 < cmax) bucket[d.w * cmax + s3] = s.w;
    atomicAdd(&outdeg[s.x], 1);
    atomicAdd(&outdeg[s.y], 1);
    atomicAdd(&outdeg[s.z], 1);
    atomicAdd(&outdeg[s.w], 1);
}

// ---- fc1 + BN statistics (sum, sumsq per feature) ------------------------
__global__ __launch_bounds__(256) void k_bnstat(const float* __restrict__ nd,
                                                const float* __restrict__ nr,
                                                const float* __restrict__ fc1w,
                                                const float* __restrict__ fc1b,
                                                float* __restrict__ stats) {
    __shared__ float sw[H1 * SDIM];
    __shared__ float sb[H1];
    __shared__ float wsum[4][H1];
    __shared__ float wsq[4][H1];
    int t = threadIdx.x;
    for (int i = t; i < H1 * SDIM; i += 256) sw[i] = fc1w[i];
    if (t < H1) sb[t] = fc1b[t];
    __syncthreads();

    int i = blockIdx.x * 256 + t;
    bool valid = i < N_NODES;
    float x[SDIM];
    if (valid) {
        const float4* p0 = (const float4*)(nd + (size_t)i * 8);
        const float4* p1 = (const float4*)(nr + (size_t)i * 8);
        float4 a0 = p0[0], a1 = p0[1], b0 = p1[0], b1 = p1[1];
        x[0]=a0.x; x[1]=a0.y; x[2]=a0.z; x[3]=a0.w;
        x[4]=a1.x; x[5]=a1.y; x[6]=a1.z; x[7]=a1.w;
        x[8]=b0.x; x[9]=b0.y; x[10]=b0.z; x[11]=b0.w;
        x[12]=b1.x; x[13]=b1.y; x[14]=b1.z; x[15]=b1.w;
    } else {
        #pragma unroll
        for (int k = 0; k < SDIM; ++k) x[k] = 0.f;
    }
    int lane = t & 63, w = t >> 6;
    for (int k = 0; k < H1; ++k) {
        float acc = sb[k];
        #pragma unroll
        for (int m = 0; m < SDIM; ++m) acc += x[m] * sw[k * SDIM + m];
        float h = valid ? fmaxf(acc, 0.f) : 0.f;
        float s = h, q = h * h;
        #pragma unroll
        for (int off = 32; off > 0; off >>= 1) {
            s += __shfl_xor(s, off);
            q += __shfl_xor(q, off);
        }
        if (lane == 0) { wsum[w][k] = s; wsq[w][k] = q; }
    }
    __syncthreads();
    if (t < H1) {
        float s = wsum[0][t] + wsum[1][t] + wsum[2][t] + wsum[3][t];
        float q = wsq[0][t] + wsq[1][t] + wsq[2][t] + wsq[3][t];
        atomicAdd(&stats[t], s);
        atomicAdd(&stats[H1 + t], q);
    }
}

// ---- fold BN affine into conv1 weight ------------------------------------
__global__ __launch_bounds__(256) void k_fold(const float* __restrict__ stats,
                                              const float* __restrict__ bng,
                                              const float* __restrict__ bnb,
                                              const float* __restrict__ c1w,
                                              float* __restrict__ W1p,
                                              float* __restrict__ cb1) {
    __shared__ float a[H1], c[H1];
    int t = threadIdx.x;
    if (t < H1) {
        float mu  = stats[t] * (1.0f / N_NODES);
        float var = stats[H1 + t] * (1.0f / N_NODES) - mu * mu;
        float av  = bng[t] / sqrtf(var + EPS_BN);
        a[t] = av;
        c[t] = bnb[t] - mu * av;
    }
    __syncthreads();
    for (int i = t; i < H1 * G1; i += 256) {
        int k = i / G1;
        W1p[i] = a[k] * c1w[i];
    }
    if (t < G1) {
        float acc = 0.f;
        for (int k = 0; k < H1; ++k) acc += c[k] * c1w[k * G1 + t];
        cb1[t] = acc;
    }
}

// ---- recompute fc1, folded BN+conv1 weight, scale by cs; bf16 rows -------
__global__ __launch_bounds__(256) void k_pre1(const float* __restrict__ nd,
                                              const float* __restrict__ nr,
                                              const float* __restrict__ fc1w,
                                              const float* __restrict__ fc1b,
                                              const float* __restrict__ W1p,
                                              const float* __restrict__ cb1,
                                              const int* __restrict__ outdeg,
                                              unsigned* __restrict__ pre) {
    __shared__ float sw[H1 * SDIM];
    __shared__ float sb[H1];
    __shared__ float sW[H1 * G1];
    __shared__ float scb[G1];
    int t = threadIdx.x;
    for (int i = t; i < H1 * SDIM; i += 256) sw[i] = fc1w[i];
    for (int i = t; i < H1 * G1; i += 256) sW[i] = W1p[i];
    if (t < H1) sb[t] = fc1b[t];
    if (t < G1) scb[t] = cb1[t];
    __syncthreads();

    int i = blockIdx.x * 256 + t;
    if (i >= N_NODES) return;

    float x[SDIM];
    {
        const float4* p0 = (const float4*)(nd + (size_t)i * 8);
        const float4* p1 = (const float4*)(nr + (size_t)i * 8);
        float4 a0 = p0[0], a1 = p0[1], b0 = p1[0], b1 = p1[1];
        x[0]=a0.x; x[1]=a0.y; x[2]=a0.z; x[3]=a0.w;
        x[4]=a1.x; x[5]=a1.y; x[6]=a1.z; x[7]=a1.w;
        x[8]=b0.x; x[9]=b0.y; x[10]=b0.z; x[11]=b0.w;
        x[12]=b1.x; x[13]=b1.y; x[14]=b1.z; x[15]=b1.w;
    }
    float o[G1];
    #pragma unroll
    for (int j = 0; j < G1; ++j) o[j] = scb[j];
    for (int k = 0; k < H1; ++k) {
        float acc = sb[k];
        #pragma unroll
        for (int m = 0; m < SDIM; ++m) acc += x[m] * sw[k * SDIM + m];
        float h = fmaxf(acc, 0.f);
        #pragma unroll
        for (int j = 0; j < G1; ++j) o[j] += h * sW[k * G1 + j];
    }
    float cs = rdeg((float)outdeg[i]);
    unsigned w[12];
    #pragma unroll
    for (int q = 0; q < 12; ++q)
        w[q] = f2bf(o[2*q] * cs) | (f2bf(o[2*q+1] * cs) << 16);
    uint4* dp = (uint4*)(pre + (size_t)i * PRE_U);
    dp[0] = make_uint4(w[0], w[1], w[2], w[3]);
    dp[1] = make_uint4(w[4], w[5], w[6], w[7]);
    dp[2] = make_uint4(w[8], w[9], w[10], w[11]);
}

// ---- gather conv1, fc2+relu, conv2-weight, fold fc3 to scalar t ----------
__global__ __launch_bounds__(256) void k_conv1fc2(const int* __restrict__ cursor,
                                                  const int* __restrict__ outdeg,
                                                  const int* __restrict__ bucket,
                                                  const unsigned* __restrict__ pre,
                                                  const float* __restrict__ action,
                                                  const float* __restrict__ c1b,
                                                  const float* __restrict__ fc2w,
                                                  const float* __restrict__ fc2b,
                                                  const float* __restrict__ c2w,
                                                  const float* __restrict__ fc3w,
                                                  float* __restrict__ tbuf,
                                                  int cmax) {
    __shared__ float s2w[H2 * (G1 + ADIM)];
    __shared__ float s2b[H2];
    __shared__ float scw[H2 * G2];
    __shared__ float s1b[G1];
    __shared__ float s3[G2];
    int t = threadIdx.x;
    for (int i = t; i < H2 * (G1 + ADIM); i += 256) s2w[i] = fc2w[i];
    for (int i = t; i < H2 * G2; i += 256) scw[i] = c2w[i];
    if (t < H2) s2b[t] = fc2b[t];
    if (t < G1) s1b[t] = c1b[t];
    if (t < G2) s3[t] = fc3w[t];
    __syncthreads();

    int i = blockIdx.x * 256 + t;
    if (i >= N_NODES) return;

    float a[G1];
    #pragma unroll
    for (int j = 0; j < G1; ++j) a[j] = 0.f;
    int d  = cursor[i];
    int dd = min(d, cmax);
    const int* row = bucket + (size_t)i * cmax;
    for (int j = 0; j < dd; ++j) {
        int s = row[j];
        const uint4* p = (const uint4*)(pre + (size_t)s * PRE_U);
        uint4 u0 = p[0], u1 = p[1], u2 = p[2];
        a[0]  += BF_LO(u0.x); a[1]  += BF_HI(u0.x);
        a[2]  += BF_LO(u0.y); a[3]  += BF_HI(u0.y);
        a[4]  += BF_LO(u0.z); a[5]  += BF_HI(u0.z);
        a[6]  += BF_LO(u0.w); a[7]  += BF_HI(u0.w);
        a[8]  += BF_LO(u1.x); a[9]  += BF_HI(u1.x);
        a[10] += BF_LO(u1.y); a[11] += BF_HI(u1.y);
        a[12] += BF_LO(u1.z); a[13] += BF_HI(u1.z);
        a[14] += BF_LO(u1.w); a[15] += BF_HI(u1.w);
        a[16] += BF_LO(u2.x); a[17] += BF_HI(u2.x);
        a[18] += BF_LO(u2.y); a[19] += BF_HI(u2.y);
        a[20] += BF_LO(u2.z); a[21] += BF_HI(u2.z);
        a[22] += BF_LO(u2.w); a[23] += BF_HI(u2.w);
    }
    float cd = rdeg((float)d);
    float x[G1 + ADIM];
    #pragma unroll
    for (int j = 0; j < G1; ++j) x[j] = a[j] * cd + s1b[j];
    {
        const float4* cp = (const float4*)(action + (size_t)i * ADIM);
        float4 a0 = cp[0], a1 = cp[1];
        x[24]=a0.x; x[25]=a0.y; x[26]=a0.z; x[27]=a0.w;
        x[28]=a1.x; x[29]=a1.y; x[30]=a1.z; x[31]=a1.w;
    }
    float o[G2];
    #pragma unroll
    for (int j = 0; j < G2; ++j) o[j] = 0.f;
    for (int k = 0; k < H2; ++k) {
        float acc = s2b[k];
        #pragma unroll
        for (int j = 0; j < G1 + ADIM; ++j) acc += x[j] * s2w[k * (G1 + ADIM) + j];
        float hv = fmaxf(acc, 0.f);
        #pragma unroll
        for (int j = 0; j < G2; ++j) o[j] += hv * scw[k * G2 + j];
    }
    float cs = rdeg((float)outdeg[i]);
    float tt = 0.f;
    #pragma unroll
    for (int j = 0; j < G2; ++j) tt += o[j] * s3[j];
    tbuf[i] = tt * cs;
}

// ---- conv2 scalar gather + per-graph pooling -----------------------------
__global__ __launch_bounds__(256) void k_pool(const int* __restrict__ cursor,
                                              const int* __restrict__ bucket,
                                              const float* __restrict__ tbuf,
                                              const int* __restrict__ gid,
                                              float* __restrict__ gsum,
                                              float* __restrict__ gcnt,
                                              int cmax) {
    __shared__ float ss[N_GRAPHS];
    __shared__ float sc[N_GRAPHS];
    int t = threadIdx.x;
    if (t < N_GRAPHS) { ss[t] = 0.f; sc[t] = 0.f; }
    __syncthreads();
    int i = blockIdx.x * 256 + t;
    if (i < N_NODES) {
        int d  = cursor[i];
        int dd = min(d, cmax);
        const int* row = bucket + (size_t)i * cmax;
        float s = 0.f;
        for (int j = 0; j < dd; ++j) s += tbuf[row[j]];
        float cd = rdeg((float)d);
        atomicAdd(&ss[gid[i]], s * cd);
        atomicAdd(&sc[gid[i]], 1.0f);
    }
    __syncthreads();
    if (t < N_GRAPHS && sc[t] != 0.f) {
        atomicAdd(&gsum[t], ss[t]);
        atomicAdd(&gcnt[t], sc[t]);
    }
}

// ---- final: mean + folded bias terms -------------------------------------
__global__ __launch_bounds__(64) void k_final(const float* __restrict__ gsum,
                                              const float* __restrict__ gcnt,
                                              const float* __restrict__ c2b,
                                              const float* __restrict__ fc3w,
                                              const float* __restrict__ fc3b,
                                              float* __restrict__ out) {
    int t = threadIdx.x;
    __shared__ float base;
    if (t == 0) {
        float a = 0.f;
        for (int j = 0; j < G2; ++j) a += c2b[j] * fc3w[j];
        base = a + fc3b[0];
    }
    __syncthreads();
    if (t < N_GRAPHS) out[t] = gsum[t] / fmaxf(gcnt[t], 1.f) + base;
}

extern "C" void kernel_launch(void* const* d_in, const int* in_sizes, int n_in,
                              void* d_out, int out_size, void* d_ws, size_t ws_size,
                              hipStream_t stream) {
    const float* nd     = (const float*)d_in[0];
    const float* nr     = (const float*)d_in[1];
    const float* action = (const float*)d_in[2];
    const int*   src    = (const int*)d_in[3];
    const int*   dst    = (const int*)d_in[4];
    const int*   gid    = (const int*)d_in[5];
    const float* fc1w   = (const float*)d_in[6];
    const float* fc1b   = (const float*)d_in[7];
    const float* bng    = (const float*)d_in[8];
    const float* bnb    = (const float*)d_in[9];
    const float* c1w    = (const float*)d_in[10];
    const float* c1b    = (const float*)d_in[11];
    const float* fc2w   = (const float*)d_in[12];
    const float* fc2b   = (const float*)d_in[13];
    const float* c2w    = (const float*)d_in[14];
    const float* c2b    = (const float*)d_in[15];
    const float* fc3w   = (const float*)d_in[16];
    const float* fc3b   = (const float*)d_in[17];
    float* out = (float*)d_out;

    const size_t N = N_NODES;
    int*      cursor = (int*)d_ws;                        // N
    int*      outdeg = cursor + N;                        // N
    unsigned* pre    = (unsigned*)(outdeg + N);           // N*16 uints (64B rows)
    float*    tbuf   = (float*)(pre + N * PRE_U);         // N
    float*    stats  = tbuf + N;                          // 80
    float*    W1p    = stats + 2 * H1;                    // 960
    float*    cb1    = W1p + H1 * G1;                     // 24
    float*    gsum   = cb1 + G1;                          // 64
    float*    gcnt   = gsum + N_GRAPHS;                   // 64
    int*      bucket = (int*)(gcnt + N_GRAPHS);           // N*cmax

    size_t used = (char*)bucket - (char*)d_ws;
    int cmax = (int)((ws_size - used) / (4 * N));
    if (cmax > 64) cmax = 64;

    hipMemsetAsync(cursor, 0, 2 * N * sizeof(int), stream);
    hipMemsetAsync(stats, 0, (2*H1 + H1*G1 + G1 + 2*N_GRAPHS) * sizeof(float), stream);

    int nb_nodes = NB_NODES;

    k_scatter<<<N_EDGES / 4 / 256, 256, 0, stream>>>((const int4*)src, (const int4*)dst,
                                                     cursor, outdeg, bucket, cmax);
    k_bnstat<<<nb_nodes, 256, 0, stream>>>(nd, nr, fc1w, fc1b, stats);
    k_fold<<<1, 256, 0, stream>>>(stats, bng, bnb, c1w, W1p, cb1);
    k_pre1<<<nb_nodes, 256, 0, stream>>>(nd, nr, fc1w, fc1b, W1p, cb1, outdeg, pre);
    k_conv1fc2<<<nb_nodes, 256, 0, stream>>>(cursor, outdeg, bucket, pre, action,
                                             c1b, fc2w, fc2b, c2w, fc3w, tbuf, cmax);
    k_pool<<<nb_nodes, 256, 0, stream>>>(cursor, bucket, tbuf, gid, gsum, gcnt, cmax);
    k_final<<<1, 64, 0, stream>>>(gsum, gcnt, c2b, fc3w, fc3b, out);
}

// Round 4
// 337.234 us; speedup vs baseline: 9.0304x; 1.6741x over previous
//
#include <hip/hip_runtime.h>

#define N_NODES 200000
#define N_EDGES 3200000
#define N_GRAPHS 64
#define SDIM 16
#define ADIM 8
#define H1 40
#define G1 24
#define H2 24
#define G2 24
#define EPS_BN 1e-5f
#define NB_NODES ((N_NODES + 255) / 256)   // 782
#define PRE_U 16      // uints per pre row (32 bf16 = 64B, 24 used)
#define BINS 391      // node bins: bin = node >> 9
#define NPB 512       // nodes per bin
#define CAP 8960      // per-bin edge capacity (Poisson(8192) + 8.5 sigma)
#define NE4 (N_EDGES / 4)   // 800000 int4 elements

static __device__ __forceinline__ float rdeg(float d) {
    return 1.0f / sqrtf(fmaxf(d, 1.0f));
}

static __device__ __forceinline__ unsigned f2bf(float f) {
    union { float f; unsigned u; } v; v.f = f;
    return (v.u + 0x7fffu + ((v.u >> 16) & 1u)) >> 16;   // RNE to bf16
}
#define BF_LO(u) __uint_as_float((u) << 16)
#define BF_HI(u) __uint_as_float((u) & 0xffff0000u)

// ---- phase A: bin edges by dst (packed dlocal|src) and by src (slocal) ----
__global__ __launch_bounds__(256) void k_bin(const int4* __restrict__ src4,
                                             const int4* __restrict__ dst4,
                                             int* __restrict__ bcD,
                                             int* __restrict__ bcS,
                                             unsigned* __restrict__ binnedD,
                                             unsigned short* __restrict__ binnedS) {
    __shared__ int histD[BINS], histS[BINS], baseD[BINS], baseS[BINS];
    __shared__ int curD[BINS], curS[BINS];
    int t = threadIdx.x;
    for (int i = t; i < BINS; i += 256) { histD[i] = 0; histS[i] = 0; curD[i] = 0; curS[i] = 0; }
    __syncthreads();
    int base = blockIdx.x * 2048;   // int4 units; 2048*4 = 8192 edges/block
    #pragma unroll
    for (int k = 0; k < 8; ++k) {
        int idx = base + k * 256 + t;
        if (idx < NE4) {
            int4 d = dst4[idx]; int4 s = src4[idx];
            atomicAdd(&histD[d.x >> 9], 1); atomicAdd(&histD[d.y >> 9], 1);
            atomicAdd(&histD[d.z >> 9], 1); atomicAdd(&histD[d.w >> 9], 1);
            atomicAdd(&histS[s.x >> 9], 1); atomicAdd(&histS[s.y >> 9], 1);
            atomicAdd(&histS[s.z >> 9], 1); atomicAdd(&histS[s.w >> 9], 1);
        }
    }
    __syncthreads();
    for (int i = t; i < BINS; i += 256) {
        baseD[i] = histD[i] ? atomicAdd(&bcD[i], histD[i]) : 0;
        baseS[i] = histS[i] ? atomicAdd(&bcS[i], histS[i]) : 0;
    }
    __syncthreads();
    #pragma unroll
    for (int k = 0; k < 8; ++k) {
        int idx = base + k * 256 + t;
        if (idx < NE4) {
            int4 d = dst4[idx]; int4 s = src4[idx];
            int dv[4] = {d.x, d.y, d.z, d.w};
            int sv[4] = {s.x, s.y, s.z, s.w};
            #pragma unroll
            for (int q = 0; q < 4; ++q) {
                int db = dv[q] >> 9, dl = dv[q] & 511;
                int slot = baseD[db] + atomicAdd(&curD[db], 1);
                if (slot < CAP)
                    binnedD[(size_t)db * CAP + slot] = ((unsigned)dl << 18) | (unsigned)sv[q];
                int sb = sv[q] >> 9, sl = sv[q] & 511;
                int slot2 = baseS[sb] + atomicAdd(&curS[sb], 1);
                if (slot2 < CAP)
                    binnedS[(size_t)sb * CAP + slot2] = (unsigned short)sl;
            }
        }
    }
}

// ---- phase B2: per-bin src counting -> outdeg ----------------------------
__global__ __launch_bounds__(256) void k_odeg(const int* __restrict__ bcS,
                                              const unsigned short* __restrict__ binnedS,
                                              int* __restrict__ outdeg) {
    __shared__ int cnt[NPB];
    int b = blockIdx.x, t = threadIdx.x;
    cnt[t] = 0; cnt[t + 256] = 0;
    __syncthreads();
    int n = min(bcS[b], CAP);
    const unsigned short* p = binnedS + (size_t)b * CAP;
    for (int i = t; i < n; i += 256) atomicAdd(&cnt[p[i]], 1);
    __syncthreads();
    int node = b * NPB + t;
    if (node < N_NODES) outdeg[node] = cnt[t];
    node += 256;
    if (node < N_NODES) outdeg[node] = cnt[t + 256];
}

// ---- phase B1: per-bin dst counting + scan -> indeg, rowstart, CSR -------
__global__ __launch_bounds__(256) void k_build(const int* __restrict__ bcD,
                                               const unsigned* __restrict__ binnedD,
                                               int* __restrict__ indeg,
                                               int* __restrict__ rowstart,
                                               int* __restrict__ csr) {
    __shared__ int cnt[NPB];
    __shared__ int excl[NPB];
    __shared__ int pairs[256];
    __shared__ int cur[NPB];
    int b = blockIdx.x, t = threadIdx.x;
    cnt[t] = 0; cnt[t + 256] = 0; cur[t] = 0; cur[t + 256] = 0;
    __syncthreads();
    int n = min(bcD[b], CAP);
    const unsigned* p = binnedD + (size_t)b * CAP;
    for (int i = t; i < n; i += 256) atomicAdd(&cnt[p[i] >> 18], 1);
    __syncthreads();
    int c0 = cnt[2 * t], c1 = cnt[2 * t + 1];
    pairs[t] = c0 + c1;
    __syncthreads();
    for (int off = 1; off < 256; off <<= 1) {
        int add = (t >= off) ? pairs[t - off] : 0;
        __syncthreads();
        pairs[t] += add;
        __syncthreads();
    }
    int ep = pairs[t] - (c0 + c1);      // exclusive pair scan
    excl[2 * t]     = ep;
    excl[2 * t + 1] = ep + c0;
    __syncthreads();
    int rowbase = b * CAP;
    int node = b * NPB + t;
    if (node < N_NODES) { indeg[node] = cnt[t]; rowstart[node] = rowbase + excl[t]; }
    int node2 = node + 256;
    if (node2 < N_NODES) { indeg[node2] = cnt[t + 256]; rowstart[node2] = rowbase + excl[t + 256]; }
    for (int i = t; i < n; i += 256) {
        unsigned v = p[i];
        int dl = v >> 18;
        int slot = excl[dl] + atomicAdd(&cur[dl], 1);
        csr[rowbase + slot] = (int)(v & 0x3FFFFu);
    }
}

// ---- fc1 + BN statistics (sum, sumsq per feature) ------------------------
__global__ __launch_bounds__(256) void k_bnstat(const float* __restrict__ nd,
                                                const float* __restrict__ nr,
                                                const float* __restrict__ fc1w,
                                                const float* __restrict__ fc1b,
                                                float* __restrict__ stats) {
    __shared__ float sw[H1 * SDIM];
    __shared__ float sb[H1];
    __shared__ float wsum[4][H1];
    __shared__ float wsq[4][H1];
    int t = threadIdx.x;
    for (int i = t; i < H1 * SDIM; i += 256) sw[i] = fc1w[i];
    if (t < H1) sb[t] = fc1b[t];
    __syncthreads();

    int i = blockIdx.x * 256 + t;
    bool valid = i < N_NODES;
    float x[SDIM];
    if (valid) {
        const float4* p0 = (const float4*)(nd + (size_t)i * 8);
        const float4* p1 = (const float4*)(nr + (size_t)i * 8);
        float4 a0 = p0[0], a1 = p0[1], b0 = p1[0], b1 = p1[1];
        x[0]=a0.x; x[1]=a0.y; x[2]=a0.z; x[3]=a0.w;
        x[4]=a1.x; x[5]=a1.y; x[6]=a1.z; x[7]=a1.w;
        x[8]=b0.x; x[9]=b0.y; x[10]=b0.z; x[11]=b0.w;
        x[12]=b1.x; x[13]=b1.y; x[14]=b1.z; x[15]=b1.w;
    } else {
        #pragma unroll
        for (int k = 0; k < SDIM; ++k) x[k] = 0.f;
    }
    int lane = t & 63, w = t >> 6;
    for (int k = 0; k < H1; ++k) {
        float acc = sb[k];
        #pragma unroll
        for (int m = 0; m < SDIM; ++m) acc += x[m] * sw[k * SDIM + m];
        float h = valid ? fmaxf(acc, 0.f) : 0.f;
        float s = h, q = h * h;
        #pragma unroll
        for (int off = 32; off > 0; off >>= 1) {
            s += __shfl_xor(s, off);
            q += __shfl_xor(q, off);
        }
        if (lane == 0) { wsum[w][k] = s; wsq[w][k] = q; }
    }
    __syncthreads();
    if (t < H1) {
        float s = wsum[0][t] + wsum[1][t] + wsum[2][t] + wsum[3][t];
        float q = wsq[0][t] + wsq[1][t] + wsq[2][t] + wsq[3][t];
        atomicAdd(&stats[t], s);
        atomicAdd(&stats[H1 + t], q);
    }
}

// ---- fold BN affine into conv1 weight ------------------------------------
__global__ __launch_bounds__(256) void k_fold(const float* __restrict__ stats,
                                              const float* __restrict__ bng,
                                              const float* __restrict__ bnb,
                                              const float* __restrict__ c1w,
                                              float* __restrict__ W1p,
                                              float* __restrict__ cb1) {
    __shared__ float a[H1], c[H1];
    int t = threadIdx.x;
    if (t < H1) {
        float mu  = stats[t] * (1.0f / N_NODES);
        float var = stats[H1 + t] * (1.0f / N_NODES) - mu * mu;
        float av  = bng[t] / sqrtf(var + EPS_BN);
        a[t] = av;
        c[t] = bnb[t] - mu * av;
    }
    __syncthreads();
    for (int i = t; i < H1 * G1; i += 256) {
        int k = i / G1;
        W1p[i] = a[k] * c1w[i];
    }
    if (t < G1) {
        float acc = 0.f;
        for (int k = 0; k < H1; ++k) acc += c[k] * c1w[k * G1 + t];
        cb1[t] = acc;
    }
}

// ---- recompute fc1, folded BN+conv1 weight, scale by cs; bf16 rows -------
__global__ __launch_bounds__(256) void k_pre1(const float* __restrict__ nd,
                                              const float* __restrict__ nr,
                                              const float* __restrict__ fc1w,
                                              const float* __restrict__ fc1b,
                                              const float* __restrict__ W1p,
                                              const float* __restrict__ cb1,
                                              const int* __restrict__ outdeg,
                                              unsigned* __restrict__ pre) {
    __shared__ float sw[H1 * SDIM];
    __shared__ float sb[H1];
    __shared__ float sW[H1 * G1];
    __shared__ float scb[G1];
    int t = threadIdx.x;
    for (int i = t; i < H1 * SDIM; i += 256) sw[i] = fc1w[i];
    for (int i = t; i < H1 * G1; i += 256) sW[i] = W1p[i];
    if (t < H1) sb[t] = fc1b[t];
    if (t < G1) scb[t] = cb1[t];
    __syncthreads();

    int i = blockIdx.x * 256 + t;
    if (i >= N_NODES) return;

    float x[SDIM];
    {
        const float4* p0 = (const float4*)(nd + (size_t)i * 8);
        const float4* p1 = (const float4*)(nr + (size_t)i * 8);
        float4 a0 = p0[0], a1 = p0[1], b0 = p1[0], b1 = p1[1];
        x[0]=a0.x; x[1]=a0.y; x[2]=a0.z; x[3]=a0.w;
        x[4]=a1.x; x[5]=a1.y; x[6]=a1.z; x[7]=a1.w;
        x[8]=b0.x; x[9]=b0.y; x[10]=b0.z; x[11]=b0.w;
        x[12]=b1.x; x[13]=b1.y; x[14]=b1.z; x[15]=b1.w;
    }
    float o[G1];
    #pragma unroll
    for (int j = 0; j < G1; ++j) o[j] = scb[j];
    for (int k = 0; k < H1; ++k) {
        float acc = sb[k];
        #pragma unroll
        for (int m = 0; m < SDIM; ++m) acc += x[m] * sw[k * SDIM + m];
        float h = fmaxf(acc, 0.f);
        #pragma unroll
        for (int j = 0; j < G1; ++j) o[j] += h * sW[k * G1 + j];
    }
    float cs = rdeg((float)outdeg[i]);
    unsigned w[12];
    #pragma unroll
    for (int q = 0; q < 12; ++q)
        w[q] = f2bf(o[2*q] * cs) | (f2bf(o[2*q+1] * cs) << 16);
    uint4* dp = (uint4*)(pre + (size_t)i * PRE_U);
    dp[0] = make_uint4(w[0], w[1], w[2], w[3]);
    dp[1] = make_uint4(w[4], w[5], w[6], w[7]);
    dp[2] = make_uint4(w[8], w[9], w[10], w[11]);
}

// ---- gather conv1, fc2+relu, conv2-weight, fold fc3 to scalar t ----------
__global__ __launch_bounds__(256) void k_conv1fc2(const int* __restrict__ rowstart,
                                                  const int* __restrict__ indeg,
                                                  const int* __restrict__ outdeg,
                                                  const int* __restrict__ csr,
                                                  const unsigned* __restrict__ pre,
                                                  const float* __restrict__ action,
                                                  const float* __restrict__ c1b,
                                                  const float* __restrict__ fc2w,
                                                  const float* __restrict__ fc2b,
                                                  const float* __restrict__ c2w,
                                                  const float* __restrict__ fc3w,
                                                  float* __restrict__ tbuf) {
    __shared__ float s2w[H2 * (G1 + ADIM)];
    __shared__ float s2b[H2];
    __shared__ float scw[H2 * G2];
    __shared__ float s1b[G1];
    __shared__ float s3[G2];
    int t = threadIdx.x;
    for (int i = t; i < H2 * (G1 + ADIM); i += 256) s2w[i] = fc2w[i];
    for (int i = t; i < H2 * G2; i += 256) scw[i] = c2w[i];
    if (t < H2) s2b[t] = fc2b[t];
    if (t < G1) s1b[t] = c1b[t];
    if (t < G2) s3[t] = fc3w[t];
    __syncthreads();

    int i = blockIdx.x * 256 + t;
    if (i >= N_NODES) return;

    float a[G1];
    #pragma unroll
    for (int j = 0; j < G1; ++j) a[j] = 0.f;
    int rs = rowstart[i];
    int d  = indeg[i];
    for (int j = rs; j < rs + d; ++j) {
        int s = csr[j];
        const uint4* p = (const uint4*)(pre + (size_t)s * PRE_U);
        uint4 u0 = p[0], u1 = p[1], u2 = p[2];
        a[0]  += BF_LO(u0.x); a[1]  += BF_HI(u0.x);
        a[2]  += BF_LO(u0.y); a[3]  += BF_HI(u0.y);
        a[4]  += BF_LO(u0.z); a[5]  += BF_HI(u0.z);
        a[6]  += BF_LO(u0.w); a[7]  += BF_HI(u0.w);
        a[8]  += BF_LO(u1.x); a[9]  += BF_HI(u1.x);
        a[10] += BF_LO(u1.y); a[11] += BF_HI(u1.y);
        a[12] += BF_LO(u1.z); a[13] += BF_HI(u1.z);
        a[14] += BF_LO(u1.w); a[15] += BF_HI(u1.w);
        a[16] += BF_LO(u2.x); a[17] += BF_HI(u2.x);
        a[18] += BF_LO(u2.y); a[19] += BF_HI(u2.y);
        a[20] += BF_LO(u2.z); a[21] += BF_HI(u2.z);
        a[22] += BF_LO(u2.w); a[23] += BF_HI(u2.w);
    }
    float cd = rdeg((float)d);
    float x[G1 + ADIM];
    #pragma unroll
    for (int j = 0; j < G1; ++j) x[j] = a[j] * cd + s1b[j];
    {
        const float4* cp = (const float4*)(action + (size_t)i * ADIM);
        float4 a0 = cp[0], a1 = cp[1];
        x[24]=a0.x; x[25]=a0.y; x[26]=a0.z; x[27]=a0.w;
        x[28]=a1.x; x[29]=a1.y; x[30]=a1.z; x[31]=a1.w;
    }
    float o[G2];
    #pragma unroll
    for (int j = 0; j < G2; ++j) o[j] = 0.f;
    for (int k = 0; k < H2; ++k) {
        float acc = s2b[k];
        #pragma unroll
        for (int j = 0; j < G1 + ADIM; ++j) acc += x[j] * s2w[k * (G1 + ADIM) + j];
        float hv = fmaxf(acc, 0.f);
        #pragma unroll
        for (int j = 0; j < G2; ++j) o[j] += hv * scw[k * G2 + j];
    }
    float cs = rdeg((float)outdeg[i]);
    float tt = 0.f;
    #pragma unroll
    for (int j = 0; j < G2; ++j) tt += o[j] * s3[j];
    tbuf[i] = tt * cs;
}

// ---- conv2 scalar gather + per-graph pooling -----------------------------
__global__ __launch_bounds__(256) void k_pool(const int* __restrict__ rowstart,
                                              const int* __restrict__ indeg,
                                              const int* __restrict__ csr,
                                              const float* __restrict__ tbuf,
                                              const int* __restrict__ gid,
                                              float* __restrict__ gsum,
                                              float* __restrict__ gcnt) {
    __shared__ float ss[N_GRAPHS];
    __shared__ float sc[N_GRAPHS];
    int t = threadIdx.x;
    if (t < N_GRAPHS) { ss[t] = 0.f; sc[t] = 0.f; }
    __syncthreads();
    int i = blockIdx.x * 256 + t;
    if (i < N_NODES) {
        int rs = rowstart[i];
        int d  = indeg[i];
        float s = 0.f;
        for (int j = rs; j < rs + d; ++j) s += tbuf[csr[j]];
        float cd = rdeg((float)d);
        atomicAdd(&ss[gid[i]], s * cd);
        atomicAdd(&sc[gid[i]], 1.0f);
    }
    __syncthreads();
    if (t < N_GRAPHS && sc[t] != 0.f) {
        atomicAdd(&gsum[t], ss[t]);
        atomicAdd(&gcnt[t], sc[t]);
    }
}

// ---- final: mean + folded bias terms -------------------------------------
__global__ __launch_bounds__(64) void k_final(const float* __restrict__ gsum,
                                              const float* __restrict__ gcnt,
                                              const float* __restrict__ c2b,
                                              const float* __restrict__ fc3w,
                                              const float* __restrict__ fc3b,
                                              float* __restrict__ out) {
    int t = threadIdx.x;
    __shared__ float base;
    if (t == 0) {
        float a = 0.f;
        for (int j = 0; j < G2; ++j) a += c2b[j] * fc3w[j];
        base = a + fc3b[0];
    }
    __syncthreads();
    if (t < N_GRAPHS) out[t] = gsum[t] / fmaxf(gcnt[t], 1.f) + base;
}

extern "C" void kernel_launch(void* const* d_in, const int* in_sizes, int n_in,
                              void* d_out, int out_size, void* d_ws, size_t ws_size,
                              hipStream_t stream) {
    const float* nd     = (const float*)d_in[0];
    const float* nr     = (const float*)d_in[1];
    const float* action = (const float*)d_in[2];
    const int*   src    = (const int*)d_in[3];
    const int*   dst    = (const int*)d_in[4];
    const int*   gid    = (const int*)d_in[5];
    const float* fc1w   = (const float*)d_in[6];
    const float* fc1b   = (const float*)d_in[7];
    const float* bng    = (const float*)d_in[8];
    const float* bnb    = (const float*)d_in[9];
    const float* c1w    = (const float*)d_in[10];
    const float* c1b    = (const float*)d_in[11];
    const float* fc2w   = (const float*)d_in[12];
    const float* fc2b   = (const float*)d_in[13];
    const float* c2w    = (const float*)d_in[14];
    const float* c2b    = (const float*)d_in[15];
    const float* fc3w   = (const float*)d_in[16];
    const float* fc3b   = (const float*)d_in[17];
    float* out = (float*)d_out;

    const size_t N = N_NODES;
    const size_t BC = (size_t)BINS * CAP;   // 3,503,360 slots
    int*      bcD      = (int*)d_ws;                    // BINS
    int*      bcS      = bcD + BINS;                    // BINS
    int*      indeg    = bcS + BINS;                    // N
    int*      outdeg   = indeg + N;                     // N
    int*      rowstart = outdeg + N;                    // N
    unsigned* binnedD  = (unsigned*)(rowstart + N);     // BINS*CAP u32
    int*      csr      = (int*)(binnedD + BC);          // BINS*CAP u32
    unsigned short* binnedS = (unsigned short*)csr;     // overlaid (dead before csr write)
    unsigned* pre      = (unsigned*)(csr + BC);         // N*PRE_U
    float*    tbuf     = (float*)(pre + N * PRE_U);     // N
    float*    stats    = tbuf + N;                      // 80
    float*    W1p      = stats + 2 * H1;                // 960
    float*    cb1      = W1p + H1 * G1;                 // 24
    float*    gsum     = cb1 + G1;                      // 64
    float*    gcnt     = gsum + N_GRAPHS;               // 64

    hipMemsetAsync(bcD, 0, 2 * BINS * sizeof(int), stream);
    hipMemsetAsync(stats, 0, (2*H1 + H1*G1 + G1 + 2*N_GRAPHS) * sizeof(float), stream);

    k_bin<<<BINS, 256, 0, stream>>>((const int4*)src, (const int4*)dst,
                                    bcD, bcS, binnedD, binnedS);
    k_bnstat<<<NB_NODES, 256, 0, stream>>>(nd, nr, fc1w, fc1b, stats);
    k_odeg<<<BINS, 256, 0, stream>>>(bcS, binnedS, outdeg);
    k_build<<<BINS, 256, 0, stream>>>(bcD, binnedD, indeg, rowstart, csr);
    k_fold<<<1, 256, 0, stream>>>(stats, bng, bnb, c1w, W1p, cb1);
    k_pre1<<<NB_NODES, 256, 0, stream>>>(nd, nr, fc1w, fc1b, W1p, cb1, outdeg, pre);
    k_conv1fc2<<<NB_NODES, 256, 0, stream>>>(rowstart, indeg, outdeg, csr, pre, action,
                                             c1b, fc2w, fc2b, c2w, fc3w, tbuf);
    k_pool<<<NB_NODES, 256, 0, stream>>>(rowstart, indeg, csr, tbuf, gid, gsum, gcnt);
    k_final<<<1, 64, 0, stream>>>(gsum, gcnt, c2b, fc3w, fc3b, out);
}

// Round 5
// 275.346 us; speedup vs baseline: 11.0601x; 1.2248x over previous
//
#include <hip/hip_runtime.h>

#define N_NODES 200000
#define N_EDGES 3200000
#define N_GRAPHS 64
#define SDIM 16
#define ADIM 8
#define H1 40
#define G1 24
#define H2 24
#define G2 24
#define EPS_BN 1e-5f
#define NB_NODES ((N_NODES + 255) / 256)   // 782
#define PRE_U 16      // uints per pre row (32 bf16 = 64B, 24 used)
#define BINS 391      // node bins: bin = node >> 9
#define NPB 512       // nodes per bin
#define CAP 8960      // per-bin edge capacity (Poisson(8192) + 8.5 sigma)
#define NE4 (N_EDGES / 4)
#define CB_N 128      // nodes per block in k_conv1fc2
#define CB_T 384      // 3 threads per node
#define PL_N 128      // nodes per block in k_pool (512 threads / 4)

static __device__ __forceinline__ float rdeg(float d) {
    return 1.0f / sqrtf(fmaxf(d, 1.0f));
}

static __device__ __forceinline__ unsigned f2bf(float f) {
    union { float f; unsigned u; } v; v.f = f;
    return (v.u + 0x7fffu + ((v.u >> 16) & 1u)) >> 16;   // RNE to bf16
}
#define BF_LO(u) __uint_as_float((u) << 16)
#define BF_HI(u) __uint_as_float((u) & 0xffff0000u)

// ---- phase A: bin edges by dst (packed dlocal|src) and by src (slocal) ----
__global__ __launch_bounds__(256) void k_bin(const int4* __restrict__ src4,
                                             const int4* __restrict__ dst4,
                                             int* __restrict__ bcD,
                                             int* __restrict__ bcS,
                                             unsigned* __restrict__ binnedD,
                                             unsigned short* __restrict__ binnedS) {
    __shared__ int histD[BINS], histS[BINS], baseD[BINS], baseS[BINS];
    __shared__ int curD[BINS], curS[BINS];
    int t = threadIdx.x;
    for (int i = t; i < BINS; i += 256) { histD[i] = 0; histS[i] = 0; curD[i] = 0; curS[i] = 0; }
    __syncthreads();
    int base = blockIdx.x * 2048;
    #pragma unroll
    for (int k = 0; k < 8; ++k) {
        int idx = base + k * 256 + t;
        if (idx < NE4) {
            int4 d = dst4[idx]; int4 s = src4[idx];
            atomicAdd(&histD[d.x >> 9], 1); atomicAdd(&histD[d.y >> 9], 1);
            atomicAdd(&histD[d.z >> 9], 1); atomicAdd(&histD[d.w >> 9], 1);
            atomicAdd(&histS[s.x >> 9], 1); atomicAdd(&histS[s.y >> 9], 1);
            atomicAdd(&histS[s.z >> 9], 1); atomicAdd(&histS[s.w >> 9], 1);
        }
    }
    __syncthreads();
    for (int i = t; i < BINS; i += 256) {
        baseD[i] = histD[i] ? atomicAdd(&bcD[i], histD[i]) : 0;
        baseS[i] = histS[i] ? atomicAdd(&bcS[i], histS[i]) : 0;
    }
    __syncthreads();
    #pragma unroll
    for (int k = 0; k < 8; ++k) {
        int idx = base + k * 256 + t;
        if (idx < NE4) {
            int4 d = dst4[idx]; int4 s = src4[idx];
            int dv[4] = {d.x, d.y, d.z, d.w};
            int sv[4] = {s.x, s.y, s.z, s.w};
            #pragma unroll
            for (int q = 0; q < 4; ++q) {
                int db = dv[q] >> 9, dl = dv[q] & 511;
                int slot = baseD[db] + atomicAdd(&curD[db], 1);
                if (slot < CAP)
                    binnedD[(size_t)db * CAP + slot] = ((unsigned)dl << 18) | (unsigned)sv[q];
                int sb = sv[q] >> 9, sl = sv[q] & 511;
                int slot2 = baseS[sb] + atomicAdd(&curS[sb], 1);
                if (slot2 < CAP)
                    binnedS[(size_t)sb * CAP + slot2] = (unsigned short)sl;
            }
        }
    }
}

// ---- phase B: per-bin outdeg count + dst count/scan -> indeg,rowstart,CSR -
__global__ __launch_bounds__(256) void k_topo(const int* __restrict__ bcD,
                                              const int* __restrict__ bcS,
                                              const unsigned* __restrict__ binnedD,
                                              const unsigned short* __restrict__ binnedS,
                                              int* __restrict__ indeg,
                                              int* __restrict__ rowstart,
                                              int* __restrict__ csr,
                                              int* __restrict__ outdeg) {
    __shared__ int cnt[NPB];
    __shared__ int excl[NPB];
    __shared__ int pairs[256];
    __shared__ int cur[NPB];
    int b = blockIdx.x, t = threadIdx.x;

    // outdeg from src-binned list
    cnt[t] = 0; cnt[t + 256] = 0;
    __syncthreads();
    int nS = min(bcS[b], CAP);
    const unsigned short* ps = binnedS + (size_t)b * CAP;
    for (int i = t; i < nS; i += 256) atomicAdd(&cnt[ps[i]], 1);
    __syncthreads();
    int node = b * NPB + t;
    if (node < N_NODES) outdeg[node] = cnt[t];
    if (node + 256 < N_NODES) outdeg[node + 256] = cnt[t + 256];
    __syncthreads();

    // indeg + rowstart + CSR from dst-binned list
    cnt[t] = 0; cnt[t + 256] = 0; cur[t] = 0; cur[t + 256] = 0;
    __syncthreads();
    int n = min(bcD[b], CAP);
    const unsigned* p = binnedD + (size_t)b * CAP;
    for (int i = t; i < n; i += 256) atomicAdd(&cnt[p[i] >> 18], 1);
    __syncthreads();
    int c0 = cnt[2 * t], c1 = cnt[2 * t + 1];
    pairs[t] = c0 + c1;
    __syncthreads();
    for (int off = 1; off < 256; off <<= 1) {
        int add = (t >= off) ? pairs[t - off] : 0;
        __syncthreads();
        pairs[t] += add;
        __syncthreads();
    }
    int ep = pairs[t] - (c0 + c1);
    excl[2 * t]     = ep;
    excl[2 * t + 1] = ep + c0;
    __syncthreads();
    int rowbase = b * CAP;
    if (node < N_NODES) { indeg[node] = cnt[t]; rowstart[node] = rowbase + excl[t]; }
    if (node + 256 < N_NODES) { indeg[node + 256] = cnt[t + 256]; rowstart[node + 256] = rowbase + excl[t + 256]; }
    for (int i = t; i < n; i += 256) {
        unsigned v = p[i];
        int dl = v >> 18;
        int slot = excl[dl] + atomicAdd(&cur[dl], 1);
        csr[rowbase + slot] = (int)(v & 0x3FFFFu);
    }
}

// ---- fc1 + BN statistics (sum, sumsq per feature) ------------------------
__global__ __launch_bounds__(256) void k_bnstat(const float* __restrict__ nd,
                                                const float* __restrict__ nr,
                                                const float* __restrict__ fc1w,
                                                const float* __restrict__ fc1b,
                                                float* __restrict__ stats) {
    __shared__ float sw[H1 * SDIM];
    __shared__ float sb[H1];
    __shared__ float wsum[4][H1];
    __shared__ float wsq[4][H1];
    int t = threadIdx.x;
    for (int i = t; i < H1 * SDIM; i += 256) sw[i] = fc1w[i];
    if (t < H1) sb[t] = fc1b[t];
    __syncthreads();

    int i = blockIdx.x * 256 + t;
    bool valid = i < N_NODES;
    float x[SDIM];
    if (valid) {
        const float4* p0 = (const float4*)(nd + (size_t)i * 8);
        const float4* p1 = (const float4*)(nr + (size_t)i * 8);
        float4 a0 = p0[0], a1 = p0[1], b0 = p1[0], b1 = p1[1];
        x[0]=a0.x; x[1]=a0.y; x[2]=a0.z; x[3]=a0.w;
        x[4]=a1.x; x[5]=a1.y; x[6]=a1.z; x[7]=a1.w;
        x[8]=b0.x; x[9]=b0.y; x[10]=b0.z; x[11]=b0.w;
        x[12]=b1.x; x[13]=b1.y; x[14]=b1.z; x[15]=b1.w;
    } else {
        #pragma unroll
        for (int k = 0; k < SDIM; ++k) x[k] = 0.f;
    }
    int lane = t & 63, w = t >> 6;
    for (int k = 0; k < H1; ++k) {
        float acc = sb[k];
        #pragma unroll
        for (int m = 0; m < SDIM; ++m) acc += x[m] * sw[k * SDIM + m];
        float h = valid ? fmaxf(acc, 0.f) : 0.f;
        float s = h, q = h * h;
        #pragma unroll
        for (int off = 32; off > 0; off >>= 1) {
            s += __shfl_xor(s, off);
            q += __shfl_xor(q, off);
        }
        if (lane == 0) { wsum[w][k] = s; wsq[w][k] = q; }
    }
    __syncthreads();
    if (t < H1) {
        float s = wsum[0][t] + wsum[1][t] + wsum[2][t] + wsum[3][t];
        float q = wsq[0][t] + wsq[1][t] + wsq[2][t] + wsq[3][t];
        atomicAdd(&stats[t], s);
        atomicAdd(&stats[H1 + t], q);
    }
}

// ---- fold BN affine into conv1 weight ------------------------------------
__global__ __launch_bounds__(256) void k_fold(const float* __restrict__ stats,
                                              const float* __restrict__ bng,
                                              const float* __restrict__ bnb,
                                              const float* __restrict__ c1w,
                                              float* __restrict__ W1p,
                                              float* __restrict__ cb1) {
    __shared__ float a[H1], c[H1];
    int t = threadIdx.x;
    if (t < H1) {
        float mu  = stats[t] * (1.0f / N_NODES);
        float var = stats[H1 + t] * (1.0f / N_NODES) - mu * mu;
        float av  = bng[t] / sqrtf(var + EPS_BN);
        a[t] = av;
        c[t] = bnb[t] - mu * av;
    }
    __syncthreads();
    for (int i = t; i < H1 * G1; i += 256) {
        int k = i / G1;
        W1p[i] = a[k] * c1w[i];
    }
    if (t < G1) {
        float acc = 0.f;
        for (int k = 0; k < H1; ++k) acc += c[k] * c1w[k * G1 + t];
        cb1[t] = acc;
    }
}

// ---- recompute fc1, folded BN+conv1 weight, scale by cs; bf16 rows -------
__global__ __launch_bounds__(256) void k_pre1(const float* __restrict__ nd,
                                              const float* __restrict__ nr,
                                              const float* __restrict__ fc1w,
                                              const float* __restrict__ fc1b,
                                              const float* __restrict__ W1p,
                                              const float* __restrict__ cb1,
                                              const int* __restrict__ outdeg,
                                              unsigned* __restrict__ pre) {
    __shared__ float sw[H1 * SDIM];
    __shared__ float sb[H1];
    __shared__ float sW[H1 * G1];
    __shared__ float scb[G1];
    int t = threadIdx.x;
    for (int i = t; i < H1 * SDIM; i += 256) sw[i] = fc1w[i];
    for (int i = t; i < H1 * G1; i += 256) sW[i] = W1p[i];
    if (t < H1) sb[t] = fc1b[t];
    if (t < G1) scb[t] = cb1[t];
    __syncthreads();

    int i = blockIdx.x * 256 + t;
    if (i >= N_NODES) return;

    float x[SDIM];
    {
        const float4* p0 = (const float4*)(nd + (size_t)i * 8);
        const float4* p1 = (const float4*)(nr + (size_t)i * 8);
        float4 a0 = p0[0], a1 = p0[1], b0 = p1[0], b1 = p1[1];
        x[0]=a0.x; x[1]=a0.y; x[2]=a0.z; x[3]=a0.w;
        x[4]=a1.x; x[5]=a1.y; x[6]=a1.z; x[7]=a1.w;
        x[8]=b0.x; x[9]=b0.y; x[10]=b0.z; x[11]=b0.w;
        x[12]=b1.x; x[13]=b1.y; x[14]=b1.z; x[15]=b1.w;
    }
    float o[G1];
    #pragma unroll
    for (int j = 0; j < G1; ++j) o[j] = scb[j];
    for (int k = 0; k < H1; ++k) {
        float acc = sb[k];
        #pragma unroll
        for (int m = 0; m < SDIM; ++m) acc += x[m] * sw[k * SDIM + m];
        float h = fmaxf(acc, 0.f);
        #pragma unroll
        for (int j = 0; j < G1; ++j) o[j] += h * sW[k * G1 + j];
    }
    float cs = rdeg((float)outdeg[i]);
    unsigned w[12];
    #pragma unroll
    for (int q = 0; q < 12; ++q)
        w[q] = f2bf(o[2*q] * cs) | (f2bf(o[2*q+1] * cs) << 16);
    uint4* dp = (uint4*)(pre + (size_t)i * PRE_U);
    dp[0] = make_uint4(w[0], w[1], w[2], w[3]);
    dp[1] = make_uint4(w[4], w[5], w[6], w[7]);
    dp[2] = make_uint4(w[8], w[9], w[10], w[11]);
}

// ---- gather conv1 (3 thr/node), fc2+relu, conv2-weight, fc3 -> scalar t ---
__global__ __launch_bounds__(CB_T) void k_conv1fc2(const int* __restrict__ rowstart,
                                                   const int* __restrict__ indeg,
                                                   const int* __restrict__ outdeg,
                                                   const int* __restrict__ csr,
                                                   const unsigned* __restrict__ pre,
                                                   const float* __restrict__ action,
                                                   const float* __restrict__ c1b,
                                                   const float* __restrict__ fc2w,
                                                   const float* __restrict__ fc2b,
                                                   const float* __restrict__ c2w,
                                                   const float* __restrict__ fc3w,
                                                   float* __restrict__ tbuf) {
    __shared__ float s2w[H2 * (G1 + ADIM)];
    __shared__ float scw[H2 * G2];
    __shared__ float s2b[H2];
    __shared__ float s1b[G1];
    __shared__ float s3[G2];
    __shared__ float agg[CB_N][25];   // pad to 25 for bank spread
    int t = threadIdx.x;
    for (int i = t; i < H2 * (G1 + ADIM); i += CB_T) s2w[i] = fc2w[i];
    for (int i = t; i < H2 * G2; i += CB_T) scw[i] = c2w[i];
    if (t < H2) s2b[t] = fc2b[t];
    if (t < G1) s1b[t] = c1b[t];
    if (t < G2) s3[t] = fc3w[t];
    __syncthreads();

    int nloc = t / 3, q = t - 3 * nloc;      // nloc in [0,128)
    int i = blockIdx.x * CB_N + nloc;
    if (nloc < CB_N && i < N_NODES) {
        float a0=0,a1=0,a2=0,a3=0,a4=0,a5=0,a6=0,a7=0;
        int rs = rowstart[i], d = indeg[i];
        int j = rs, je = rs + d;
        for (; j + 1 < je; j += 2) {
            int s0 = csr[j], s1 = csr[j + 1];
            uint4 u0 = *((const uint4*)(pre + (size_t)s0 * PRE_U) + q);
            uint4 u1 = *((const uint4*)(pre + (size_t)s1 * PRE_U) + q);
            a0 += BF_LO(u0.x); a1 += BF_HI(u0.x); a2 += BF_LO(u0.y); a3 += BF_HI(u0.y);
            a4 += BF_LO(u0.z); a5 += BF_HI(u0.z); a6 += BF_LO(u0.w); a7 += BF_HI(u0.w);
            a0 += BF_LO(u1.x); a1 += BF_HI(u1.x); a2 += BF_LO(u1.y); a3 += BF_HI(u1.y);
            a4 += BF_LO(u1.z); a5 += BF_HI(u1.z); a6 += BF_LO(u1.w); a7 += BF_HI(u1.w);
        }
        if (j < je) {
            uint4 u0 = *((const uint4*)(pre + (size_t)csr[j] * PRE_U) + q);
            a0 += BF_LO(u0.x); a1 += BF_HI(u0.x); a2 += BF_LO(u0.y); a3 += BF_HI(u0.y);
            a4 += BF_LO(u0.z); a5 += BF_HI(u0.z); a6 += BF_LO(u0.w); a7 += BF_HI(u0.w);
        }
        float* ar = &agg[nloc][q * 8];
        ar[0]=a0; ar[1]=a1; ar[2]=a2; ar[3]=a3; ar[4]=a4; ar[5]=a5; ar[6]=a6; ar[7]=a7;
    }
    __syncthreads();

    if (t < CB_N) {
        int i2 = blockIdx.x * CB_N + t;
        if (i2 < N_NODES) {
            int d = indeg[i2];
            float cd = rdeg((float)d);
            float x[G1 + ADIM];
            #pragma unroll
            for (int j = 0; j < G1; ++j) x[j] = agg[t][j] * cd + s1b[j];
            {
                const float4* cp = (const float4*)(action + (size_t)i2 * ADIM);
                float4 v0 = cp[0], v1 = cp[1];
                x[24]=v0.x; x[25]=v0.y; x[26]=v0.z; x[27]=v0.w;
                x[28]=v1.x; x[29]=v1.y; x[30]=v1.z; x[31]=v1.w;
            }
            float o[G2];
            #pragma unroll
            for (int j = 0; j < G2; ++j) o[j] = 0.f;
            for (int k = 0; k < H2; ++k) {
                float acc = s2b[k];
                #pragma unroll
                for (int j = 0; j < G1 + ADIM; ++j) acc += x[j] * s2w[k * (G1 + ADIM) + j];
                float hv = fmaxf(acc, 0.f);
                #pragma unroll
                for (int j = 0; j < G2; ++j) o[j] += hv * scw[k * G2 + j];
            }
            float cs = rdeg((float)outdeg[i2]);
            float tt = 0.f;
            #pragma unroll
            for (int j = 0; j < G2; ++j) tt += o[j] * s3[j];
            tbuf[i2] = tt * cs;
        }
    }
}

// ---- conv2 scalar gather (4 thr/node) + per-graph pooling -----------------
__global__ __launch_bounds__(512) void k_pool(const int* __restrict__ rowstart,
                                              const int* __restrict__ indeg,
                                              const int* __restrict__ csr,
                                              const float* __restrict__ tbuf,
                                              const int* __restrict__ gid,
                                              float* __restrict__ gsum,
                                              float* __restrict__ gcnt) {
    __shared__ float ss[N_GRAPHS];
    __shared__ float sc[N_GRAPHS];
    int t = threadIdx.x;
    if (t < N_GRAPHS) { ss[t] = 0.f; sc[t] = 0.f; }
    __syncthreads();
    int nloc = t >> 2, h = t & 3;
    int i = blockIdx.x * PL_N + nloc;
    bool ok = i < N_NODES;
    float s = 0.f;
    int d = 0, g = -1;
    if (ok) {
        int rs = rowstart[i];
        d = indeg[i];
        for (int j = rs + h; j < rs + d; j += 4) s += tbuf[csr[j]];
        g = gid[i];
    }
    s += __shfl_xor(s, 1);
    s += __shfl_xor(s, 2);
    // wave-uniform graph fast path (gids sorted -> almost always uniform)
    float sv = (ok && h == 0) ? s * rdeg((float)d) : 0.f;
    float cv = (ok && h == 0) ? 1.f : 0.f;
    int gfirst = __shfl(g, 0);
    bool uni = __all(g == gfirst || g < 0) && gfirst >= 0;
    if (uni) {
        #pragma unroll
        for (int off = 32; off >= 4; off >>= 1) {
            sv += __shfl_xor(sv, off);
            cv += __shfl_xor(cv, off);
        }
        sv += __shfl_xor(sv, 2); sv += __shfl_xor(sv, 1);
        cv += __shfl_xor(cv, 2); cv += __shfl_xor(cv, 1);
        if ((t & 63) == 0) {
            atomicAdd(&ss[gfirst], sv);
            atomicAdd(&sc[gfirst], cv);
        }
    } else if (ok && h == 0) {
        atomicAdd(&ss[g], s * rdeg((float)d));
        atomicAdd(&sc[g], 1.f);
    }
    __syncthreads();
    if (t < N_GRAPHS && sc[t] != 0.f) {
        atomicAdd(&gsum[t], ss[t]);
        atomicAdd(&gcnt[t], sc[t]);
    }
}

// ---- final: mean + folded bias terms -------------------------------------
__global__ __launch_bounds__(64) void k_final(const float* __restrict__ gsum,
                                              const float* __restrict__ gcnt,
                                              const float* __restrict__ c2b,
                                              const float* __restrict__ fc3w,
                                              const float* __restrict__ fc3b,
                                              float* __restrict__ out) {
    int t = threadIdx.x;
    __shared__ float base;
    if (t == 0) {
        float a = 0.f;
        for (int j = 0; j < G2; ++j) a += c2b[j] * fc3w[j];
        base = a + fc3b[0];
    }
    __syncthreads();
    if (t < N_GRAPHS) out[t] = gsum[t] / fmaxf(gcnt[t], 1.f) + base;
}

extern "C" void kernel_launch(void* const* d_in, const int* in_sizes, int n_in,
                              void* d_out, int out_size, void* d_ws, size_t ws_size,
                              hipStream_t stream) {
    const float* nd     = (const float*)d_in[0];
    const float* nr     = (const float*)d_in[1];
    const float* action = (const float*)d_in[2];
    const int*   src    = (const int*)d_in[3];
    const int*   dst    = (const int*)d_in[4];
    const int*   gid    = (const int*)d_in[5];
    const float* fc1w   = (const float*)d_in[6];
    const float* fc1b   = (const float*)d_in[7];
    const float* bng    = (const float*)d_in[8];
    const float* bnb    = (const float*)d_in[9];
    const float* c1w    = (const float*)d_in[10];
    const float* c1b    = (const float*)d_in[11];
    const float* fc2w   = (const float*)d_in[12];
    const float* fc2b   = (const float*)d_in[13];
    const float* c2w    = (const float*)d_in[14];
    const float* c2b    = (const float*)d_in[15];
    const float* fc3w   = (const float*)d_in[16];
    const float* fc3b   = (const float*)d_in[17];
    float* out = (float*)d_out;

    const size_t N = N_NODES;
    const size_t BC = (size_t)BINS * CAP;   // 3,503,360 slots
    int*      ws       = (int*)d_ws;
    int*      bcD      = ws;                            // BINS
    int*      bcS      = bcD + BINS;                    // BINS
    unsigned* pre      = (unsigned*)(ws + 800);         // N*PRE_U (16B-aligned: 800*4=3200)
    int*      indeg    = (int*)(pre + N * PRE_U);       // N
    int*      outdeg   = indeg + N;                     // N
    int*      rowstart = outdeg + N;                    // N
    unsigned* binnedD  = (unsigned*)(rowstart + N);     // BC u32
    unsigned short* binnedS = (unsigned short*)(binnedD + BC);  // BC u16
    int*      csr      = (int*)(binnedS + BC);          // BC u32
    float*    tbuf     = (float*)(csr + BC);            // N
    float*    stats    = tbuf + N;                      // 80
    float*    W1p      = stats + 2 * H1;                // 960
    float*    cb1      = W1p + H1 * G1;                 // 24
    float*    gsum     = cb1 + G1;                      // 64
    float*    gcnt     = gsum + N_GRAPHS;               // 64

    hipMemsetAsync(bcD, 0, 2 * BINS * sizeof(int), stream);
    hipMemsetAsync(stats, 0, (2*H1 + H1*G1 + G1 + 2*N_GRAPHS) * sizeof(float), stream);

    k_bin<<<BINS, 256, 0, stream>>>((const int4*)src, (const int4*)dst,
                                    bcD, bcS, binnedD, binnedS);
    k_bnstat<<<NB_NODES, 256, 0, stream>>>(nd, nr, fc1w, fc1b, stats);
    k_topo<<<BINS, 256, 0, stream>>>(bcD, bcS, binnedD, binnedS,
                                     indeg, rowstart, csr, outdeg);
    k_fold<<<1, 256, 0, stream>>>(stats, bng, bnb, c1w, W1p, cb1);
    k_pre1<<<NB_NODES, 256, 0, stream>>>(nd, nr, fc1w, fc1b, W1p, cb1, outdeg, pre);
    k_conv1fc2<<<(N_NODES + CB_N - 1) / CB_N, CB_T, 0, stream>>>(
        rowstart, indeg, outdeg, csr, pre, action,
        c1b, fc2w, fc2b, c2w, fc3w, tbuf);
    k_pool<<<(N_NODES + PL_N - 1) / PL_N, 512, 0, stream>>>(
        rowstart, indeg, csr, tbuf, gid, gsum, gcnt);
    k_final<<<1, 64, 0, stream>>>(gsum, gcnt, c2b, fc3w, fc3b, out);
}